// Round 14
// baseline (721.765 us; speedup 1.0000x reference)
//
#include <hip/hip_runtime.h>

#define NN 50000
#define NE 800000
#define D 128
#define NCLS 47
#define ZPAD 64   // padded width for projected layer-2 features
#define LN_EPS 1e-5f

// ---------------- CSR build ----------------
__global__ void k_count(const int* __restrict__ dst, int* __restrict__ counts) {
  int i = blockIdx.x * blockDim.x + threadIdx.x;
  if (i < NE) atomicAdd(&counts[dst[i]], 1);
}

__global__ void k_scan1(const int* __restrict__ counts, int* __restrict__ excl,
                        int* __restrict__ bsum) {
  __shared__ int tmp[256];
  int t = threadIdx.x, i = blockIdx.x * 256 + t;
  int v = (i < NN) ? counts[i] : 0;
  tmp[t] = v;
  __syncthreads();
  for (int off = 1; off < 256; off <<= 1) {
    int u = (t >= off) ? tmp[t - off] : 0;
    __syncthreads();
    tmp[t] += u;
    __syncthreads();
  }
  if (i < NN) excl[i] = tmp[t] - v;
  if (t == 255) bsum[blockIdx.x] = tmp[255];
}

__global__ void k_scan2(int* __restrict__ bsum, int nb) {
  __shared__ int tmp[256];
  int t = threadIdx.x;
  int v = (t < nb) ? bsum[t] : 0;
  tmp[t] = v;
  __syncthreads();
  for (int off = 1; off < 256; off <<= 1) {
    int u = (t >= off) ? tmp[t - off] : 0;
    __syncthreads();
    tmp[t] += u;
    __syncthreads();
  }
  if (t < nb) bsum[t] = tmp[t] - v;
}

__global__ void k_scan3(int* __restrict__ indptr, const int* __restrict__ bsum,
                        int* __restrict__ cursor) {
  int i = blockIdx.x * 256 + threadIdx.x;
  if (i < NN) {
    int v = indptr[i] + bsum[i >> 8];
    indptr[i] = v;
    cursor[i] = v;
  }
  if (i == 0) indptr[NN] = NE;
}

__global__ void k_scatter(const int* __restrict__ src, const int* __restrict__ dst,
                          int* __restrict__ cursor, int* __restrict__ esrc) {
  int i = blockIdx.x * blockDim.x + threadIdx.x;
  if (i < NE) {
    int d = dst[i];
    int pos = atomicAdd(&cursor[d], 1);
    esrc[pos] = src[i];
  }
}

// ---------------- mean aggregation, XCD-sliced (L2-resident gather) ----------------
// slice = bid & 7 -> same XCD under round-robin dispatch; per-XCD working set
// = 50000 x 16 cols x 4B = 3.2 MB -> fits the 4 MB XCD L2. One wave per node:
// 8 edge-slots x 8 lanes x float2 (one load instr = 8 edges x 64 B = 512 B).
// 2 gathers in flight per slot; slot-reduce = 3-step shfl_xor butterfly.
__global__ __launch_bounds__(256) void k_agg(const float* __restrict__ feat,
                                             const int* __restrict__ indptr,
                                             const int* __restrict__ esrc,
                                             float* __restrict__ out) {
  int bid = blockIdx.x;
  int slice = bid & 7;
  int node = (bid >> 3) * 4 + (threadIdx.x >> 6);
  if (node >= NN) return;
  int lane = threadIdx.x & 63;
  int slot = lane >> 3;   // 8 edge slots
  int cp = lane & 7;      // col pair within slice
  int colbase = slice * 16 + cp * 2;
  const float* fp = feat + colbase;
  int beg = indptr[node], end = indptr[node + 1];
  float a0 = 0.f, a1 = 0.f;
  int e = beg + slot;
  for (; e + 8 < end; e += 16) {  // 2 rounds (16 edges) in flight
    int s0 = esrc[e], s1 = esrc[e + 8];
    float2 v0 = *(const float2*)(fp + (size_t)s0 * D);
    float2 v1 = *(const float2*)(fp + (size_t)s1 * D);
    a0 += v0.x + v1.x;
    a1 += v0.y + v1.y;
  }
  if (e < end) {
    float2 v0 = *(const float2*)(fp + (size_t)esrc[e] * D);
    a0 += v0.x;
    a1 += v0.y;
  }
  a0 += __shfl_xor(a0, 8, 64);  a1 += __shfl_xor(a1, 8, 64);
  a0 += __shfl_xor(a0, 16, 64); a1 += __shfl_xor(a1, 16, 64);
  a0 += __shfl_xor(a0, 32, 64); a1 += __shfl_xor(a1, 32, 64);
  if (slot == 0) {
    float inv = 1.0f / fmaxf((float)(end - beg), 1.0f);
    float2 o;
    o.x = a0 * inv;
    o.y = a1 * inv;
    *(float2*)(out + (size_t)node * D + colbase) = o;
  }
}

// ---------------- fused dual-GEMM + LN + ReLU (hidden layers) ----------------
// R10/R12 triple-measured form: 32 rows/block, 4 waves, batched ds_read_b128
// (8 in flight), weights pipelined 1 chunk ahead. (256,4): VGPR cap 128; the
// ~64-live working set NEEDS it (R9: (256,5) -> 48 regs, serialize+spill,
// 129 vs 72.9 us). DO NOT change the bound.
__global__ __launch_bounds__(256, 4) void k_gemm_ln(
    const float* __restrict__ h, const float* __restrict__ hn,
    const float* __restrict__ ws, const float* __restrict__ wn,
    const float* __restrict__ b, const float* __restrict__ g,
    const float* __restrict__ be, float* __restrict__ out) {
  __shared__ float lds[32][256];  // cols [0,128)=h, [128,256)=hn (32 KB)
  int tid = threadIdx.x;
  int row0 = blockIdx.x * 32;
  for (int i = tid; i < 32 * 64; i += 256) {  // float4 granules, 64 per row
    int r = i >> 6, q = i & 63;
    int row = row0 + r;
    float4 v = make_float4(0.f, 0.f, 0.f, 0.f);
    if (row < NN) {
      const float* p = (q < 32) ? (h + (size_t)row * D + q * 4)
                                : (hn + (size_t)row * D + (q - 32) * 4);
      v = *(const float4*)p;
    }
    *(float4*)&lds[r][q * 4] = v;
  }
  __syncthreads();

  int wv = tid >> 6, lane = tid & 63;
  int rbase = wv * 8;
  float acc0[8], acc1[8];
#pragma unroll
  for (int r = 0; r < 8; ++r) { acc0[r] = 0.f; acc1[r] = 0.f; }

  float cw[8], nw[8];
#pragma unroll
  for (int j = 0; j < 4; ++j) {  // preload chunk 0 (self rows 0..3)
    cw[2 * j]     = ws[j * 128 + lane];
    cw[2 * j + 1] = ws[j * 128 + lane + 64];
  }
#pragma unroll 2
  for (int c = 0; c < 64; ++c) {
    int cn = (c + 1 < 64) ? c + 1 : 63;
    const float* np = ((cn & 32) ? wn : ws) + (cn & 31) * 512;
    float4 hv[8];
#pragma unroll
    for (int r = 0; r < 8; ++r) hv[r] = *(const float4*)&lds[rbase + r][c * 4];
#pragma unroll
    for (int j = 0; j < 4; ++j) {
      nw[2 * j]     = np[j * 128 + lane];
      nw[2 * j + 1] = np[j * 128 + lane + 64];
    }
#pragma unroll
    for (int r = 0; r < 8; ++r) {
      acc0[r] = fmaf(hv[r].x, cw[0], acc0[r]);
      acc1[r] = fmaf(hv[r].x, cw[1], acc1[r]);
      acc0[r] = fmaf(hv[r].y, cw[2], acc0[r]);
      acc1[r] = fmaf(hv[r].y, cw[3], acc1[r]);
      acc0[r] = fmaf(hv[r].z, cw[4], acc0[r]);
      acc1[r] = fmaf(hv[r].z, cw[5], acc1[r]);
      acc0[r] = fmaf(hv[r].w, cw[6], acc0[r]);
      acc1[r] = fmaf(hv[r].w, cw[7], acc1[r]);
    }
#pragma unroll
    for (int j = 0; j < 8; ++j) cw[j] = nw[j];
  }

  float bj0 = b[lane], bj1 = b[lane + 64];
  float gj0 = g[lane], gj1 = g[lane + 64];
  float ej0 = be[lane], ej1 = be[lane + 64];
#pragma unroll
  for (int r = 0; r < 8; ++r) {
    float v0 = acc0[r] + bj0, v1 = acc1[r] + bj1;
    float s = v0 + v1, q2 = v0 * v0 + v1 * v1;
#pragma unroll
    for (int off = 1; off < 64; off <<= 1) {
      s += __shfl_xor(s, off, 64);
      q2 += __shfl_xor(q2, off, 64);
    }
    float mu = s * (1.0f / 128.0f);
    float var = q2 * (1.0f / 128.0f) - mu * mu;
    float rs = rsqrtf(var + LN_EPS);
    float o0 = fmaxf((v0 - mu) * rs * gj0 + ej0, 0.f);
    float o1 = fmaxf((v1 - mu) * rs * gj1 + ej1, 0.f);
    int row = row0 + rbase + r;
    if (row < NN) {
      out[(size_t)row * D + lane] = o0;
      out[(size_t)row * D + lane + 64] = o1;
    }
  }
}

// ---------------- layer 2: project h2 through BOTH weight matrices ----------------
// (256,4): VGPR cap 128 -- fits, NO spill (R8 disaster at (256,8) is the warning).
__global__ __launch_bounds__(256, 4) void k_gemm_proj2(
    const float* __restrict__ h, const float* __restrict__ ws,
    const float* __restrict__ wn, const float* __restrict__ b,
    float* __restrict__ s2p, float* __restrict__ z2) {
  __shared__ float lds[32][128];  // 16 KB
  int tid = threadIdx.x;
  int row0 = blockIdx.x * 32;
  for (int i = tid; i < 32 * 32; i += 256) {
    int r = i >> 5, q = i & 31;
    int row = row0 + r;
    float4 v = make_float4(0.f, 0.f, 0.f, 0.f);
    if (row < NN) v = *(const float4*)(h + (size_t)row * D + q * 4);
    *(float4*)&lds[r][q * 4] = v;
  }
  __syncthreads();

  int wv = tid >> 6, lane = tid & 63;
  int rbase = wv * 8;
  bool act = lane < NCLS;
  float accS[8], accZ[8];
#pragma unroll
  for (int r = 0; r < 8; ++r) { accS[r] = 0.f; accZ[r] = 0.f; }

  float cw[8], nw[8];
#pragma unroll
  for (int j = 0; j < 4; ++j) {
    cw[j]     = act ? ws[j * NCLS + lane] : 0.f;
    cw[4 + j] = act ? wn[j * NCLS + lane] : 0.f;
  }
#pragma unroll 2
  for (int c = 0; c < 32; ++c) {
    int cn = (c + 1 < 32) ? c + 1 : 31;
    float4 hv[8];
#pragma unroll
    for (int r = 0; r < 8; ++r) hv[r] = *(const float4*)&lds[rbase + r][c * 4];
#pragma unroll
    for (int j = 0; j < 4; ++j) {
      nw[j]     = act ? ws[(cn * 4 + j) * NCLS + lane] : 0.f;
      nw[4 + j] = act ? wn[(cn * 4 + j) * NCLS + lane] : 0.f;
    }
#pragma unroll
    for (int r = 0; r < 8; ++r) {
      accS[r] = fmaf(hv[r].x, cw[0], accS[r]);
      accZ[r] = fmaf(hv[r].x, cw[4], accZ[r]);
      accS[r] = fmaf(hv[r].y, cw[1], accS[r]);
      accZ[r] = fmaf(hv[r].y, cw[5], accZ[r]);
      accS[r] = fmaf(hv[r].z, cw[2], accS[r]);
      accZ[r] = fmaf(hv[r].z, cw[6], accZ[r]);
      accS[r] = fmaf(hv[r].w, cw[3], accS[r]);
      accZ[r] = fmaf(hv[r].w, cw[7], accZ[r]);
    }
#pragma unroll
    for (int j = 0; j < 8; ++j) cw[j] = nw[j];
  }

  float bj = act ? b[lane] : 0.f;
#pragma unroll
  for (int r = 0; r < 8; ++r) {
    int row = row0 + rbase + r;
    if (row < NN) {
      z2[(size_t)row * ZPAD + lane] = act ? accZ[r] : 0.f;  // pad cols ZERO
      s2p[(size_t)row * ZPAD + lane] = accS[r] + bj;
    }
  }
}

// ---------------- layer 2 final agg, XCD-sliced (8 cols/slice; slices>=6 idle) ----------------
// Per-XCD z2 working set = 50000 x 8 x 4B = 1.6 MB -> L2-resident.
// Wave = 16 edge-slots x 4 lanes x float2; slot-reduce = 4-step butterfly.
__global__ __launch_bounds__(256) void k_agg2(const float* __restrict__ z2,
                                              const float* __restrict__ s2p,
                                              const int* __restrict__ indptr,
                                              const int* __restrict__ esrc,
                                              float* __restrict__ out) {
  int bid = blockIdx.x;
  int slice = bid & 7;
  if (slice >= 6) return;  // cols 48..63 are pad
  int node = (bid >> 3) * 4 + (threadIdx.x >> 6);
  if (node >= NN) return;
  int lane = threadIdx.x & 63;
  int slot = lane >> 2;   // 16 edge slots
  int cp = lane & 3;      // col pair within slice
  int colbase = slice * 8 + cp * 2;
  const float* zp = z2 + colbase;
  int beg = indptr[node], end = indptr[node + 1];
  float a0 = 0.f, a1 = 0.f;
  int e = beg + slot;
  for (; e + 16 < end; e += 32) {  // 2 rounds (32 edges) in flight
    int s0 = esrc[e], s1 = esrc[e + 16];
    float2 v0 = *(const float2*)(zp + (size_t)s0 * ZPAD);
    float2 v1 = *(const float2*)(zp + (size_t)s1 * ZPAD);
    a0 += v0.x + v1.x;
    a1 += v0.y + v1.y;
  }
  if (e < end) {
    float2 v0 = *(const float2*)(zp + (size_t)esrc[e] * ZPAD);
    a0 += v0.x;
    a1 += v0.y;
  }
  a0 += __shfl_xor(a0, 4, 64);  a1 += __shfl_xor(a1, 4, 64);
  a0 += __shfl_xor(a0, 8, 64);  a1 += __shfl_xor(a1, 8, 64);
  a0 += __shfl_xor(a0, 16, 64); a1 += __shfl_xor(a1, 16, 64);
  a0 += __shfl_xor(a0, 32, 64); a1 += __shfl_xor(a1, 32, 64);
  if (slot == 0) {
    float inv = 1.0f / fmaxf((float)(end - beg), 1.0f);
    int col = colbase;
    if (col < NCLS)
      out[(size_t)node * NCLS + col] = s2p[(size_t)node * ZPAD + col] + a0 * inv;
    if (col + 1 < NCLS)
      out[(size_t)node * NCLS + col + 1] = s2p[(size_t)node * ZPAD + col + 1] + a1 * inv;
  }
}

// ---------------- launch ----------------
extern "C" void kernel_launch(void* const* d_in, const int* in_sizes, int n_in,
                              void* d_out, int out_size, void* d_ws, size_t ws_size,
                              hipStream_t stream) {
  (void)in_sizes; (void)n_in; (void)out_size; (void)ws_size;
  const float* x       = (const float*)d_in[0];
  const int*   src     = (const int*)d_in[1];
  const int*   dst     = (const int*)d_in[2];
  const float* w_self0 = (const float*)d_in[3];
  const float* w_nei0  = (const float*)d_in[4];
  const float* b0      = (const float*)d_in[5];
  const float* g0      = (const float*)d_in[6];
  const float* be0     = (const float*)d_in[7];
  const float* w_self1 = (const float*)d_in[8];
  const float* w_nei1  = (const float*)d_in[9];
  const float* b1      = (const float*)d_in[10];
  const float* g1      = (const float*)d_in[11];
  const float* be1     = (const float*)d_in[12];
  const float* w_self2 = (const float*)d_in[13];
  const float* w_nei2  = (const float*)d_in[14];
  const float* b2      = (const float*)d_in[15];
  float* outp = (float*)d_out;

  char* ws = (char*)d_ws;
  size_t off = 0;
  auto alloc = [&](size_t bytes) -> void* {
    off = (off + 255) & ~(size_t)255;
    void* p = ws + off;
    off += bytes;
    return p;
  };
  int*   counts = (int*)alloc(NN * sizeof(int));
  int*   indptr = (int*)alloc((NN + 1) * sizeof(int));
  int*   cursor = (int*)alloc(NN * sizeof(int));
  int*   bsum   = (int*)alloc(256 * sizeof(int));
  int*   esrc   = (int*)alloc(NE * sizeof(int));
  float* hn     = (float*)alloc((size_t)NN * D * sizeof(float));  // also z2 (layer 2)
  float* h1     = (float*)alloc((size_t)NN * D * sizeof(float));  // also s2p (layer 2)
  float* h2     = (float*)alloc((size_t)NN * D * sizeof(float));
  float* z2  = hn;  // 12.8 MB into 25.6 MB slot (hn dead at layer 2)
  float* s2p = h1;  // h1 dead once h2 exists

  const int nbScan = (NN + 255) / 256;  // 196

  // CSR build
  hipMemsetAsync(counts, 0, NN * sizeof(int), stream);
  k_count<<<(NE + 255) / 256, 256, 0, stream>>>(dst, counts);
  k_scan1<<<nbScan, 256, 0, stream>>>(counts, indptr, bsum);
  k_scan2<<<1, 256, 0, stream>>>(bsum, nbScan);
  k_scan3<<<nbScan, 256, 0, stream>>>(indptr, bsum, cursor);
  k_scatter<<<(NE + 255) / 256, 256, 0, stream>>>(src, dst, cursor, esrc);

  const int gemmBlocks = (NN + 31) / 32;          // 1563
  const int aggBlocks  = ((NN + 3) / 4) * 8;      // 100000 (4 nodes/block x 8 slices)

  // layer 0
  k_agg<<<aggBlocks, 256, 0, stream>>>(x, indptr, esrc, hn);
  k_gemm_ln<<<gemmBlocks, 256, 0, stream>>>(x, hn, w_self0, w_nei0, b0, g0, be0, h1);
  // layer 1
  k_agg<<<aggBlocks, 256, 0, stream>>>(h1, indptr, esrc, hn);
  k_gemm_ln<<<gemmBlocks, 256, 0, stream>>>(h1, hn, w_self1, w_nei1, b1, g1, be1, h2);
  // layer 2: project first (agg commutes with the linear map), then sliced agg
  k_gemm_proj2<<<gemmBlocks, 256, 0, stream>>>(h2, w_self2, w_nei2, b2, s2p, z2);
  k_agg2<<<aggBlocks, 256, 0, stream>>>(z2, s2p, indptr, esrc, outp);
}